// Round 7
// baseline (614.674 us; speedup 1.0000x reference)
//
#include <hip/hip_runtime.h>
#include <stdint.h>

typedef unsigned short u16;
typedef __bf16 bf16x8 __attribute__((ext_vector_type(8)));
typedef float f32x4 __attribute__((ext_vector_type(4)));
typedef float f32x2 __attribute__((ext_vector_type(2)));
typedef uint32_t u32x2 __attribute__((ext_vector_type(2)));
typedef uint32_t u32x4 __attribute__((ext_vector_type(4)));
typedef u16 u16x2 __attribute__((ext_vector_type(2)));

#define DEV static __device__ __forceinline__

constexpr int T = 2048;
constexpr int C = 2048;
constexpr int QKC = 2560;  // q (2048) + k (512) fp32 post-projection columns
constexpr int KVC = 512;

DEV u16 f2bf(float f) {
  union { float f; uint32_t u; } v; v.f = f;
  return (u16)((v.u + 0x7fffu + ((v.u >> 16) & 1u)) >> 16);
}
DEV float bf2f(u16 u) {
  union { uint32_t u; float f; } v; v.u = ((uint32_t)u) << 16;
  return v.f;
}

// ------------- x -> bf16 hi/lo split (x4 vectorized) -------------
__global__ __launch_bounds__(256) void k_cvt2(const float* __restrict__ in,
                                              u16* __restrict__ oh,
                                              u16* __restrict__ ol, int n4) {
  int i = blockIdx.x * 256 + threadIdx.x;
  if (i >= n4) return;
  f32x4 f = ((const f32x4*)in)[i];
  u16 h[4], lo[4];
#pragma unroll
  for (int j = 0; j < 4; j++) {
    h[j] = f2bf(f[j]);
    lo[j] = f2bf(f[j] - bf2f(h[j]));
  }
  u32x2 ph, pl;
  ph.x = (uint32_t)h[0] | ((uint32_t)h[1] << 16);
  ph.y = (uint32_t)h[2] | ((uint32_t)h[3] << 16);
  pl.x = (uint32_t)lo[0] | ((uint32_t)lo[1] << 16);
  pl.y = (uint32_t)lo[2] | ((uint32_t)lo[3] << 16);
  ((u32x2*)oh)[i] = ph;
  ((u32x2*)ol)[i] = pl;
}

// ---- transpose + cvt(+split): in [R][Cc] f32 -> oh/ol [Cc][R] bf16 ----
template <bool LO>
__global__ __launch_bounds__(256) void k_tcvt2(const float* __restrict__ in,
                                               u16* __restrict__ oh,
                                               u16* __restrict__ ol, int R, int Cc) {
  __shared__ u16 th[32][33];
  __shared__ u16 tl[32][33];
  int c0 = blockIdx.x * 32, r0 = blockIdx.y * 32;
  int tx = threadIdx.x, ty = threadIdx.y;  // 32 x 8
#pragma unroll
  for (int i = 0; i < 4; i++) {
    float f = in[(size_t)(r0 + ty + i * 8) * Cc + c0 + tx];
    u16 h = f2bf(f);
    th[ty + i * 8][tx] = h;
    if constexpr (LO) tl[ty + i * 8][tx] = f2bf(f - bf2f(h));
  }
  __syncthreads();
#pragma unroll
  for (int i = 0; i < 4; i++) {
    oh[(size_t)(c0 + ty + i * 8) * R + r0 + tx] = th[tx][ty + i * 8];
    if constexpr (LO)
      ol[(size_t)(c0 + ty + i * 8) * R + r0 + tx] = tl[tx][ty + i * 8];
  }
}

DEV void gload16(const u16* g, u16* lds) {
  __builtin_amdgcn_global_load_lds(
      (const __attribute__((address_space(1))) void*)g,
      (__attribute__((address_space(3))) void*)lds, 16, 0, 0);
}

// ---- fused QKV projection. QK cols (n0<2560): 3-term split bf16, fp32 out.
// ---- V cols: single bf16 product, bf16 out.
__global__ __launch_bounds__(256) void k_gemmqkv(const u16* __restrict__ xh,
                                                 const u16* __restrict__ xl,
                                                 const u16* __restrict__ BTh,
                                                 const u16* __restrict__ BTl,
                                                 float* __restrict__ QKf,
                                                 u16* __restrict__ Vb) {
  __shared__ __align__(16) u16 As[128 * 32];
  __shared__ __align__(16) u16 Bs[128 * 32];
  const int tid = threadIdx.x;
  const int w = tid >> 6, l = tid & 63;
  const int m0 = blockIdx.y << 7, n0 = blockIdx.x << 7;
  const int wr = (w >> 1) * 64, wc = (w & 1) * 64;
  const int g = l >> 4, c = l & 15;
  const bool isV = (n0 >= 2560);
  const int nseg = isV ? 1 : 3;

  const size_t aoff = (size_t)(m0 + w * 32 + (l >> 2)) * C + (l & 3) * 8;
  const size_t boff = (size_t)(n0 + w * 32 + (l >> 2)) * C + (l & 3) * 8;
  u16* la = &As[(w * 32) * 32];
  u16* lb = &Bs[(w * 32) * 32];

  f32x4 acc[4][4] = {};

  for (int seg = 0; seg < nseg; ++seg) {
    const u16* ga = ((seg == 2) ? xl : xh) + aoff;
    const u16* gb = ((seg == 1) ? BTl : BTh) + boff;
    for (int k0 = 0; k0 < C; k0 += 32) {
      gload16(ga + k0, la);
      gload16(ga + k0 + 16 * C, la + 16 * 32);
      gload16(gb + k0, lb);
      gload16(gb + k0 + 16 * C, lb + 16 * 32);
      __syncthreads();
      bf16x8 af[4], bfr[4];
#pragma unroll
      for (int m = 0; m < 4; m++)
        af[m] = *(const bf16x8*)&As[(wr + m * 16 + c) * 32 + g * 8];
#pragma unroll
      for (int n = 0; n < 4; n++)
        bfr[n] = *(const bf16x8*)&Bs[(wc + n * 16 + c) * 32 + g * 8];
#pragma unroll
      for (int m = 0; m < 4; m++)
#pragma unroll
        for (int n = 0; n < 4; n++)
          acc[m][n] = __builtin_amdgcn_mfma_f32_16x16x32_bf16(af[m], bfr[n], acc[m][n], 0, 0, 0);
      __syncthreads();
    }
  }

#pragma unroll
  for (int m = 0; m < 4; m++) {
    int row = m0 + wr + m * 16 + g * 4;
#pragma unroll
    for (int n = 0; n < 4; n++) {
#pragma unroll
      for (int j = 0; j < 4; j++) {
        if (!isV) {
          int col = n0 + wc + n * 16 + c;
          QKf[(size_t)(row + j) * QKC + col] = acc[m][n][j];
        } else {
          int col = n0 - 2560 + wc + n * 16 + c;
          Vb[(size_t)(row + j) * KVC + col] = f2bf(acc[m][n][j]);
        }
      }
    }
  }
}

// ---- generic bf16 GEMM (final projection): A[M][K] * BT[N][K] -> fp32 C ----
__global__ __launch_bounds__(256) void k_gemm(const u16* __restrict__ A,
                                              const u16* __restrict__ BT,
                                              float* __restrict__ Cout,
                                              int M, int N, int K) {
  __shared__ __align__(16) u16 As[128 * 32];
  __shared__ __align__(16) u16 Bs[128 * 32];
  const int tid = threadIdx.x;
  const int w = tid >> 6, l = tid & 63;
  const int m0 = blockIdx.y << 7, n0 = blockIdx.x << 7;
  const int wr = (w >> 1) * 64, wc = (w & 1) * 64;
  const int g = l >> 4, c = l & 15;

  f32x4 acc[4][4] = {};
  const u16* ga = A + (size_t)(m0 + w * 32 + (l >> 2)) * K + (l & 3) * 8;
  const u16* gb = BT + (size_t)(n0 + w * 32 + (l >> 2)) * K + (l & 3) * 8;
  u16* la = &As[(w * 32) * 32];
  u16* lb = &Bs[(w * 32) * 32];

  for (int k0 = 0; k0 < K; k0 += 32) {
    gload16(ga + k0, la);
    gload16(ga + k0 + (size_t)16 * K, la + 16 * 32);
    gload16(gb + k0, lb);
    gload16(gb + k0 + (size_t)16 * K, lb + 16 * 32);
    __syncthreads();
    bf16x8 af[4], bfr[4];
#pragma unroll
    for (int m = 0; m < 4; m++)
      af[m] = *(const bf16x8*)&As[(wr + m * 16 + c) * 32 + g * 8];
#pragma unroll
    for (int n = 0; n < 4; n++)
      bfr[n] = *(const bf16x8*)&Bs[(wc + n * 16 + c) * 32 + g * 8];
#pragma unroll
    for (int m = 0; m < 4; m++)
#pragma unroll
      for (int n = 0; n < 4; n++)
        acc[m][n] = __builtin_amdgcn_mfma_f32_16x16x32_bf16(af[m], bfr[n], acc[m][n], 0, 0, 0);
    __syncthreads();
  }

#pragma unroll
  for (int m = 0; m < 4; m++) {
    int row = m0 + wr + m * 16 + g * 4;
#pragma unroll
    for (int n = 0; n < 4; n++) {
      int col = n0 + wc + n * 16 + c;
#pragma unroll
      for (int j = 0; j < 4; j++)
        Cout[(size_t)(row + j) * N + col] = acc[m][n][j];
    }
  }
}

// ---- LayerNorm(128) from fp32 projections -> split bf16 hi/lo ----
DEV void ln_row_f32(const float* __restrict__ x, const float* __restrict__ g,
                    u16* __restrict__ oh, u16* __restrict__ ol, int l) {
  f32x2 v = ((const f32x2*)x)[l];
  float s = v.x + v.y;
  float s2 = v.x * v.x + v.y * v.y;
#pragma unroll
  for (int m = 1; m < 64; m <<= 1) {
    s += __shfl_xor(s, m);
    s2 += __shfl_xor(s2, m);
  }
  float mu = s * (1.f / 128.f);
  float var = s2 * (1.f / 128.f) - mu * mu;
  float r = rsqrtf(var + 1e-5f);
  f32x2 gg = ((const f32x2*)g)[l];
  float y0 = (v.x - mu) * r * gg.x;
  float y1 = (v.y - mu) * r * gg.y;
  u16 h0 = f2bf(y0), h1 = f2bf(y1);
  u16x2 oh2, ol2;
  oh2.x = h0; oh2.y = h1;
  ol2.x = f2bf(y0 - bf2f(h0)); ol2.y = f2bf(y1 - bf2f(h1));
  ((u16x2*)oh)[l] = oh2;
  ((u16x2*)ol)[l] = ol2;
}

__global__ __launch_bounds__(256) void k_ln(const float* __restrict__ QKf,
                                            const float* __restrict__ gq,
                                            const float* __restrict__ gk,
                                            u16* __restrict__ Qh, u16* __restrict__ Ql,
                                            u16* __restrict__ Kh, u16* __restrict__ Kl) {
  int t = blockIdx.x;
  int w = threadIdx.x >> 6, l = threadIdx.x & 63;
  const float* row = QKf + (size_t)t * QKC;
#pragma unroll
  for (int i = 0; i < 4; i++) {
    int h = w * 4 + i;
    ln_row_f32(row + h * 128, gq, Qh + (size_t)t * C + h * 128,
               Ql + (size_t)t * C + h * 128, l);
  }
  ln_row_f32(row + 2048 + w * 128, gk, Kh + (size_t)t * KVC + w * 128,
             Kl + (size_t)t * KVC + w * 128, l);
}

// ---- causal GQA flash attention, split-bf16 QK^T (3 products) ----
__global__ __launch_bounds__(256) void k_attn(const u16* __restrict__ Qh_,
                                              const u16* __restrict__ Ql_,
                                              const u16* __restrict__ Kh_,
                                              const u16* __restrict__ Kl_,
                                              const u16* __restrict__ Vb,
                                              const float* __restrict__ temp,
                                              u16* __restrict__ Ob) {
  constexpr int VS = 40;
  __shared__ __align__(16) u16 Vt[128 * VS];
  __shared__ __align__(16) u16 Pl[4][16 * 32];
  const int h = blockIdx.y, kh = h >> 2;
  const int q0 = blockIdx.x << 6;
  const int tid = threadIdx.x;
  const int w = tid >> 6, l = tid & 63;
  const int g = l >> 4, c = l & 15;
  const float scale = fminf(expf(temp[0]), 50.f);

  bf16x8 qfh[4], qfl[4];
  {
    const size_t qo = (size_t)(q0 + w * 16 + c) * C + h * 128 + g * 8;
#pragma unroll
    for (int kk = 0; kk < 4; kk++) {
      qfh[kk] = *(const bf16x8*)(Qh_ + qo + kk * 32);
      qfl[kk] = *(const bf16x8*)(Ql_ + qo + kk * 32);
    }
  }

  f32x4 o[8] = {};
  float mi[4], li[4];
#pragma unroll
  for (int j = 0; j < 4; j++) { mi[j] = -INFINITY; li[j] = 0.f; }

  const int vs_s = tid & 31, vd0 = (tid >> 5) * 16;
  const int send = q0 + 64;
  for (int s0 = 0; s0 < send; s0 += 32) {
    __syncthreads();
    {  // stage V tile transposed: Vt[d][s]
      const u16* vsrc = Vb + (size_t)(s0 + vs_s) * KVC + kh * 128 + vd0;
      u16 tmp[16];
      *(u32x4*)&tmp[0] = *(const u32x4*)vsrc;
      *(u32x4*)&tmp[8] = *(const u32x4*)(vsrc + 8);
#pragma unroll
      for (int j = 0; j < 16; j++) Vt[(vd0 + j) * VS + vs_s] = tmp[j];
    }
    __syncthreads();

    f32x4 sc[2] = {};
#pragma unroll
    for (int tile = 0; tile < 2; tile++) {
      const size_t ko = (size_t)(s0 + tile * 16 + c) * KVC + kh * 128 + g * 8;
#pragma unroll
      for (int kk = 0; kk < 4; kk++) {
        bf16x8 kfh = *(const bf16x8*)(Kh_ + ko + kk * 32);
        bf16x8 kfl = *(const bf16x8*)(Kl_ + ko + kk * 32);
        sc[tile] = __builtin_amdgcn_mfma_f32_16x16x32_bf16(qfh[kk], kfh, sc[tile], 0, 0, 0);
        sc[tile] = __builtin_amdgcn_mfma_f32_16x16x32_bf16(qfh[kk], kfl, sc[tile], 0, 0, 0);
        sc[tile] = __builtin_amdgcn_mfma_f32_16x16x32_bf16(qfl[kk], kfh, sc[tile], 0, 0, 0);
      }
    }

#pragma unroll
    for (int j = 0; j < 4; j++) {
      const int q = q0 + w * 16 + g * 4 + j;
      float x0 = sc[0][j] * scale; if (s0 + c > q) x0 = -INFINITY;
      float x1 = sc[1][j] * scale; if (s0 + 16 + c > q) x1 = -INFINITY;
      float mx = fmaxf(x0, x1);
#pragma unroll
      for (int msk = 1; msk < 16; msk <<= 1) mx = fmaxf(mx, __shfl_xor(mx, msk));
      float mn = fmaxf(mi[j], mx);
      float a = __expf(mi[j] - mn);
      float p0 = __expf(x0 - mn);
      float p1 = __expf(x1 - mn);
      float rs = p0 + p1;
#pragma unroll
      for (int msk = 1; msk < 16; msk <<= 1) rs += __shfl_xor(rs, msk);
      li[j] = li[j] * a + rs;
      mi[j] = mn;
#pragma unroll
      for (int dt = 0; dt < 8; dt++) o[dt][j] *= a;
      Pl[w][(g * 4 + j) * 32 + c] = f2bf(p0);
      Pl[w][(g * 4 + j) * 32 + 16 + c] = f2bf(p1);
    }

    bf16x8 pa = *(const bf16x8*)&Pl[w][c * 32 + g * 8];
#pragma unroll
    for (int dt = 0; dt < 8; dt++) {
      bf16x8 vf = *(const bf16x8*)&Vt[(dt * 16 + c) * VS + g * 8];
      o[dt] = __builtin_amdgcn_mfma_f32_16x16x32_bf16(pa, vf, o[dt], 0, 0, 0);
    }
  }

#pragma unroll
  for (int j = 0; j < 4; j++) {
    float inv = 1.f / li[j];
    u16* orow = Ob + (size_t)(q0 + w * 16 + g * 4 + j) * C + h * 128;
#pragma unroll
    for (int dt = 0; dt < 8; dt++) orow[dt * 16 + c] = f2bf(o[dt][j] * inv);
  }
}

extern "C" void kernel_launch(void* const* d_in, const int* in_sizes, int n_in,
                              void* d_out, int out_size, void* d_ws, size_t ws_size,
                              hipStream_t stream) {
  const float* x = (const float*)d_in[0];
  const float* Wq = (const float*)d_in[1];
  const float* Wk = (const float*)d_in[2];
  const float* Wv = (const float*)d_in[3];
  const float* Wo = (const float*)d_in[4];
  const float* gq = (const float*)d_in[5];
  const float* gk = (const float*)d_in[6];
  const float* temp = (const float*)d_in[7];
  float* out = (float*)d_out;

  constexpr size_t M1 = (size_t)1024 * 1024;
  u16* ws16 = (u16*)d_ws;
  u16* xh  = ws16;                 // 4M u16
  u16* xl  = xh + 4 * M1;          // 4M
  u16* BTh = xl + 4 * M1;          // 6M  [3072][2048]: WqT_hi | WkT_hi | WvT
  u16* BTl = BTh + 6 * M1;         // 5M  [2560][2048]: WqT_lo | WkT_lo
  u16* WoT = BTl + 5 * M1;         // 4M
  u16* Vb  = WoT + 4 * M1;         // 1M  [2048][512]
  float* QKf = (float*)(Vb + 1 * M1);  // 5M f32 [2048][2560]
  // aliases (disjoint liveness): after k_gemmqkv, BTh/BTl are dead.
  u16* Qh = BTl;                   // 4M
  u16* Ql = BTh;                   // 4M
  u16* Kh = BTh + 4 * M1;          // 1M
  u16* Kl = BTh + 5 * M1;          // 1M
  u16* Ob = xh;                    // 4M (xh dead after k_gemmqkv)

  // 1) x -> bf16 hi/lo
  k_cvt2<<<(T * C / 4 + 255) / 256, 256, 0, stream>>>(x, xh, xl, T * C / 4);
  // 2) weights -> transposed bf16 (split for Wq/Wk)
  k_tcvt2<true><<<dim3(C / 32, C / 32), dim3(32, 8), 0, stream>>>(Wq, BTh, BTl, C, C);
  k_tcvt2<true><<<dim3(KVC / 32, C / 32), dim3(32, 8), 0, stream>>>(
      Wk, BTh + (size_t)C * C, BTl + (size_t)C * C, C, KVC);
  k_tcvt2<false><<<dim3(KVC / 32, C / 32), dim3(32, 8), 0, stream>>>(
      Wv, BTh + (size_t)2560 * C, nullptr, C, KVC);
  k_tcvt2<false><<<dim3(C / 32, C / 32), dim3(32, 8), 0, stream>>>(Wo, WoT, nullptr, C, C);
  // 3) fused QKV projection (QK: 3-term split -> fp32; V: bf16)
  k_gemmqkv<<<dim3(3072 / 128, T / 128), 256, 0, stream>>>(xh, xl, BTh, BTl, QKf, Vb);
  // 4) LN on q,k heads (fp32 in, split bf16 out)
  k_ln<<<T, 256, 0, stream>>>(QKf, gq, gk, Qh, Ql, Kh, Kl);
  // 5) causal GQA flash attention
  k_attn<<<dim3(T / 64, 16), 256, 0, stream>>>(Qh, Ql, Kh, Kl, Vb, temp, Ob);
  // 6) output projection
  k_gemm<<<dim3(C / 128, T / 128), 256, 0, stream>>>(Ob, WoT, out, T, C, C);

  (void)in_sizes; (void)n_in; (void)out_size; (void)ws_size;
}

// Round 9
// 497.176 us; speedup vs baseline: 1.2363x; 1.2363x over previous
//
#include <hip/hip_runtime.h>
#include <stdint.h>

typedef unsigned short u16;
typedef __bf16 bf16x8 __attribute__((ext_vector_type(8)));
typedef float f32x4 __attribute__((ext_vector_type(4)));
typedef float f32x2 __attribute__((ext_vector_type(2)));
typedef uint32_t u32x2 __attribute__((ext_vector_type(2)));
typedef uint32_t u32x4 __attribute__((ext_vector_type(4)));
typedef u16 u16x2 __attribute__((ext_vector_type(2)));

#define DEV static __device__ __forceinline__

constexpr int T = 2048;
constexpr int C = 2048;
constexpr int QKC = 2560;
constexpr int KVC = 512;

DEV u16 f2bf(float f) {
  union { float f; uint32_t u; } v; v.f = f;
  return (u16)((v.u + 0x7fffu + ((v.u >> 16) & 1u)) >> 16);
}
DEV float bf2f(u16 u) {
  union { uint32_t u; float f; } v; v.u = ((uint32_t)u) << 16;
  return v.f;
}

// ------------- x -> bf16 hi/lo split -------------
__global__ __launch_bounds__(256) void k_cvt2(const float* __restrict__ in,
                                              u16* __restrict__ oh,
                                              u16* __restrict__ ol, int n4) {
  int i = blockIdx.x * 256 + threadIdx.x;
  if (i >= n4) return;
  f32x4 f = ((const f32x4*)in)[i];
  u16 h[4], lo[4];
#pragma unroll
  for (int j = 0; j < 4; j++) {
    h[j] = f2bf(f[j]);
    lo[j] = f2bf(f[j] - bf2f(h[j]));
  }
  u32x2 ph, pl;
  ph.x = (uint32_t)h[0] | ((uint32_t)h[1] << 16);
  ph.y = (uint32_t)h[2] | ((uint32_t)h[3] << 16);
  pl.x = (uint32_t)lo[0] | ((uint32_t)lo[1] << 16);
  pl.y = (uint32_t)lo[2] | ((uint32_t)lo[3] << 16);
  ((u32x2*)oh)[i] = ph;
  ((u32x2*)ol)[i] = pl;
}

// ---- transpose + cvt(+split) ----
template <bool LO>
__global__ __launch_bounds__(256) void k_tcvt2(const float* __restrict__ in,
                                               u16* __restrict__ oh,
                                               u16* __restrict__ ol, int R, int Cc) {
  __shared__ u16 th[32][33];
  __shared__ u16 tl[32][33];
  int c0 = blockIdx.x * 32, r0 = blockIdx.y * 32;
  int tx = threadIdx.x, ty = threadIdx.y;
#pragma unroll
  for (int i = 0; i < 4; i++) {
    float f = in[(size_t)(r0 + ty + i * 8) * Cc + c0 + tx];
    u16 h = f2bf(f);
    th[ty + i * 8][tx] = h;
    if constexpr (LO) tl[ty + i * 8][tx] = f2bf(f - bf2f(h));
  }
  __syncthreads();
#pragma unroll
  for (int i = 0; i < 4; i++) {
    oh[(size_t)(c0 + ty + i * 8) * R + r0 + tx] = th[tx][ty + i * 8];
    if constexpr (LO)
      ol[(size_t)(c0 + ty + i * 8) * R + r0 + tx] = tl[tx][ty + i * 8];
  }
}

DEV void gload16(const u16* g, u16* lds) {
  __builtin_amdgcn_global_load_lds(
      (const __attribute__((address_space(1))) void*)g,
      (__attribute__((address_space(3))) void*)lds, 16, 0, 0);
}

// ---- fused QKV projection: single K-pass, 3 split-products into one acc ----
__global__ __launch_bounds__(256) void k_gemmqkv(const u16* __restrict__ xh,
                                                 const u16* __restrict__ xl,
                                                 const u16* __restrict__ BTh,
                                                 const u16* __restrict__ BTl,
                                                 float* __restrict__ QKf,
                                                 u16* __restrict__ Vb) {
  __shared__ __align__(16) u16 Ahs[128 * 32];
  __shared__ __align__(16) u16 Als[128 * 32];
  __shared__ __align__(16) u16 Bhs[128 * 32];
  __shared__ __align__(16) u16 Bls[128 * 32];
  const int tid = threadIdx.x;
  const int w = tid >> 6, l = tid & 63;
  const int m0 = blockIdx.y << 7, n0 = blockIdx.x << 7;
  const int wr = (w >> 1) * 64, wc = (w & 1) * 64;
  const int g = l >> 4, c = l & 15;
  const bool isV = (n0 >= 2560);

  const size_t aoff = (size_t)(m0 + w * 32 + (l >> 2)) * C + (l & 3) * 8;
  const size_t boff = (size_t)(n0 + w * 32 + (l >> 2)) * C + (l & 3) * 8;
  u16* lah = &Ahs[(w * 32) * 32];
  u16* lal = &Als[(w * 32) * 32];
  u16* lbh = &Bhs[(w * 32) * 32];
  u16* lbl = &Bls[(w * 32) * 32];

  f32x4 acc[4][4] = {};

  for (int k0 = 0; k0 < C; k0 += 32) {
    gload16(xh + aoff + k0, lah);
    gload16(xh + aoff + k0 + 16 * C, lah + 16 * 32);
    gload16(BTh + boff + k0, lbh);
    gload16(BTh + boff + k0 + 16 * C, lbh + 16 * 32);
    if (!isV) {
      gload16(xl + aoff + k0, lal);
      gload16(xl + aoff + k0 + 16 * C, lal + 16 * 32);
      gload16(BTl + boff + k0, lbl);
      gload16(BTl + boff + k0 + 16 * C, lbl + 16 * 32);
    }
    __syncthreads();
    bf16x8 afh[4], bfh[4];
#pragma unroll
    for (int m = 0; m < 4; m++)
      afh[m] = *(const bf16x8*)&Ahs[(wr + m * 16 + c) * 32 + g * 8];
#pragma unroll
    for (int n = 0; n < 4; n++)
      bfh[n] = *(const bf16x8*)&Bhs[(wc + n * 16 + c) * 32 + g * 8];
#pragma unroll
    for (int m = 0; m < 4; m++)
#pragma unroll
      for (int n = 0; n < 4; n++)
        acc[m][n] = __builtin_amdgcn_mfma_f32_16x16x32_bf16(afh[m], bfh[n], acc[m][n], 0, 0, 0);
    if (!isV) {
      bf16x8 bfl[4];
#pragma unroll
      for (int n = 0; n < 4; n++)
        bfl[n] = *(const bf16x8*)&Bls[(wc + n * 16 + c) * 32 + g * 8];
#pragma unroll
      for (int m = 0; m < 4; m++)
#pragma unroll
        for (int n = 0; n < 4; n++)
          acc[m][n] = __builtin_amdgcn_mfma_f32_16x16x32_bf16(afh[m], bfl[n], acc[m][n], 0, 0, 0);
      bf16x8 afl[4];
#pragma unroll
      for (int m = 0; m < 4; m++)
        afl[m] = *(const bf16x8*)&Als[(wr + m * 16 + c) * 32 + g * 8];
#pragma unroll
      for (int m = 0; m < 4; m++)
#pragma unroll
        for (int n = 0; n < 4; n++)
          acc[m][n] = __builtin_amdgcn_mfma_f32_16x16x32_bf16(afl[m], bfh[n], acc[m][n], 0, 0, 0);
    }
    __syncthreads();
  }

#pragma unroll
  for (int m = 0; m < 4; m++) {
    int row = m0 + wr + m * 16 + g * 4;
#pragma unroll
    for (int n = 0; n < 4; n++) {
#pragma unroll
      for (int j = 0; j < 4; j++) {
        if (!isV) {
          int col = n0 + wc + n * 16 + c;
          QKf[(size_t)(row + j) * QKC + col] = acc[m][n][j];
        } else {
          int col = n0 - 2560 + wc + n * 16 + c;
          Vb[(size_t)(row + j) * KVC + col] = f2bf(acc[m][n][j]);
        }
      }
    }
  }
}

// ---- generic bf16 GEMM (final projection) ----
__global__ __launch_bounds__(256) void k_gemm(const u16* __restrict__ A,
                                              const u16* __restrict__ BT,
                                              float* __restrict__ Cout,
                                              int M, int N, int K) {
  __shared__ __align__(16) u16 As[128 * 32];
  __shared__ __align__(16) u16 Bs[128 * 32];
  const int tid = threadIdx.x;
  const int w = tid >> 6, l = tid & 63;
  const int m0 = blockIdx.y << 7, n0 = blockIdx.x << 7;
  const int wr = (w >> 1) * 64, wc = (w & 1) * 64;
  const int g = l >> 4, c = l & 15;

  f32x4 acc[4][4] = {};
  const u16* ga = A + (size_t)(m0 + w * 32 + (l >> 2)) * K + (l & 3) * 8;
  const u16* gb = BT + (size_t)(n0 + w * 32 + (l >> 2)) * K + (l & 3) * 8;
  u16* la = &As[(w * 32) * 32];
  u16* lb = &Bs[(w * 32) * 32];

  for (int k0 = 0; k0 < K; k0 += 32) {
    gload16(ga + k0, la);
    gload16(ga + k0 + (size_t)16 * K, la + 16 * 32);
    gload16(gb + k0, lb);
    gload16(gb + k0 + (size_t)16 * K, lb + 16 * 32);
    __syncthreads();
    bf16x8 af[4], bfr[4];
#pragma unroll
    for (int m = 0; m < 4; m++)
      af[m] = *(const bf16x8*)&As[(wr + m * 16 + c) * 32 + g * 8];
#pragma unroll
    for (int n = 0; n < 4; n++)
      bfr[n] = *(const bf16x8*)&Bs[(wc + n * 16 + c) * 32 + g * 8];
#pragma unroll
    for (int m = 0; m < 4; m++)
#pragma unroll
      for (int n = 0; n < 4; n++)
        acc[m][n] = __builtin_amdgcn_mfma_f32_16x16x32_bf16(af[m], bfr[n], acc[m][n], 0, 0, 0);
    __syncthreads();
  }

#pragma unroll
  for (int m = 0; m < 4; m++) {
    int row = m0 + wr + m * 16 + g * 4;
#pragma unroll
    for (int n = 0; n < 4; n++) {
      int col = n0 + wc + n * 16 + c;
#pragma unroll
      for (int j = 0; j < 4; j++)
        Cout[(size_t)(row + j) * N + col] = acc[m][n][j];
    }
  }
}

// ---- LayerNorm(128) -> split bf16 hi/lo ----
DEV void ln_row_f32(const float* __restrict__ x, const float* __restrict__ g,
                    u16* __restrict__ oh, u16* __restrict__ ol, int l) {
  f32x2 v = ((const f32x2*)x)[l];
  float s = v.x + v.y;
  float s2 = v.x * v.x + v.y * v.y;
#pragma unroll
  for (int m = 1; m < 64; m <<= 1) {
    s += __shfl_xor(s, m);
    s2 += __shfl_xor(s2, m);
  }
  float mu = s * (1.f / 128.f);
  float var = s2 * (1.f / 128.f) - mu * mu;
  float r = rsqrtf(var + 1e-5f);
  f32x2 gg = ((const f32x2*)g)[l];
  float y0 = (v.x - mu) * r * gg.x;
  float y1 = (v.y - mu) * r * gg.y;
  u16 h0 = f2bf(y0), h1 = f2bf(y1);
  u16x2 oh2, ol2;
  oh2.x = h0; oh2.y = h1;
  ol2.x = f2bf(y0 - bf2f(h0)); ol2.y = f2bf(y1 - bf2f(h1));
  ((u16x2*)oh)[l] = oh2;
  ((u16x2*)ol)[l] = ol2;
}

__global__ __launch_bounds__(256) void k_ln(const float* __restrict__ QKf,
                                            const float* __restrict__ gq,
                                            const float* __restrict__ gk,
                                            u16* __restrict__ Qh, u16* __restrict__ Ql,
                                            u16* __restrict__ Kh, u16* __restrict__ Kl) {
  int t = blockIdx.x;
  int w = threadIdx.x >> 6, l = threadIdx.x & 63;
  const float* row = QKf + (size_t)t * QKC;
#pragma unroll
  for (int i = 0; i < 4; i++) {
    int h = w * 4 + i;
    ln_row_f32(row + h * 128, gq, Qh + (size_t)t * C + h * 128,
               Ql + (size_t)t * C + h * 128, l);
  }
  ln_row_f32(row + 2048 + w * 128, gk, Kh + (size_t)t * KVC + w * 128,
             Kl + (size_t)t * KVC + w * 128, l);
}

// ---- causal GQA flash attention: SBLK=64, sum-via-MFMA ones-column,
// ---- early V prefetch, descending-q0 balance ----
__global__ __launch_bounds__(256) void k_attn(const u16* __restrict__ Qh_,
                                              const u16* __restrict__ Ql_,
                                              const u16* __restrict__ Kh_,
                                              const u16* __restrict__ Kl_,
                                              const u16* __restrict__ Vb,
                                              const float* __restrict__ temp,
                                              u16* __restrict__ Ob) {
  constexpr int VS = 72;                     // row stride (u16): pad -> 2-way banks
  __shared__ __align__(16) u16 Vt[144 * VS]; // rows 0..127 V^T, 128..143 ones-tile
  __shared__ __align__(16) u16 Pl[4][16 * VS];
  const int flat = blockIdx.x;               // 512 blocks; longest first
  const int qt = 31 - (flat >> 4);
  const int h = flat & 15, kh = h >> 2;
  const int q0 = qt << 6;
  const int tid = threadIdx.x;
  const int w = tid >> 6, l = tid & 63;
  const int g = l >> 4, c = l & 15;
  const float scale = fminf(__expf(temp[0]), 50.f);

  // ones-tile init: d-col 128 (c==0 row) = 1.0 over s<64, rest 0
  for (int idx = tid; idx < 16 * VS; idx += 256) {
    int r = idx / VS, s = idx - r * VS;
    Vt[(128 + r) * VS + s] = (r == 0 && s < 64) ? (u16)0x3F80 : (u16)0;
  }

  bf16x8 qfh[4], qfl[4];
  {
    const size_t qo = (size_t)(q0 + w * 16 + c) * C + h * 128 + g * 8;
#pragma unroll
    for (int kk = 0; kk < 4; kk++) {
      qfh[kk] = *(const bf16x8*)(Qh_ + qo + kk * 32);
      qfl[kk] = *(const bf16x8*)(Ql_ + qo + kk * 32);
    }
  }

  f32x4 o[8] = {};
  f32x4 o2 = {0.f, 0.f, 0.f, 0.f};   // denominator accumulator (col 0 = row-sum)
  float mi[4];
#pragma unroll
  for (int j = 0; j < 4; j++) mi[j] = -INFINITY;

  const int vs_s = tid & 63, vd0 = (tid >> 6) * 32;
  const int nit = qt + 1;

  union { u32x4 v4[4]; u16 h16[32]; } vst;
  {
    const u16* vsrc = Vb + (size_t)vs_s * KVC + kh * 128 + vd0;
    vst.v4[0] = *(const u32x4*)(vsrc);
    vst.v4[1] = *(const u32x4*)(vsrc + 8);
    vst.v4[2] = *(const u32x4*)(vsrc + 16);
    vst.v4[3] = *(const u32x4*)(vsrc + 24);
  }

  for (int it = 0; it < nit; ++it) {
    const int s0 = it << 6;
    __syncthreads();  // prev iter's Vt readers done
#pragma unroll
    for (int j = 0; j < 32; ++j) Vt[(vd0 + j) * VS + vs_s] = vst.h16[j];
    __syncthreads();
    if (it + 1 < nit) {  // prefetch next V tile; latency hides under compute
      const u16* vsrc = Vb + (size_t)((it + 1) * 64 + vs_s) * KVC + kh * 128 + vd0;
      vst.v4[0] = *(const u32x4*)(vsrc);
      vst.v4[1] = *(const u32x4*)(vsrc + 8);
      vst.v4[2] = *(const u32x4*)(vsrc + 16);
      vst.v4[3] = *(const u32x4*)(vsrc + 24);
    }

    // QK^T: 4 col-tiles of 16 s, split-bf16 3-product
    f32x4 sc[4] = {};
#pragma unroll
    for (int t = 0; t < 4; ++t) {
      const size_t ko = (size_t)(s0 + t * 16 + c) * KVC + kh * 128 + g * 8;
#pragma unroll
      for (int kk = 0; kk < 4; ++kk) {
        bf16x8 kfh = *(const bf16x8*)(Kh_ + ko + kk * 32);
        bf16x8 kfl = *(const bf16x8*)(Kl_ + ko + kk * 32);
        sc[t] = __builtin_amdgcn_mfma_f32_16x16x32_bf16(qfh[kk], kfh, sc[t], 0, 0, 0);
        sc[t] = __builtin_amdgcn_mfma_f32_16x16x32_bf16(qfh[kk], kfl, sc[t], 0, 0, 0);
        sc[t] = __builtin_amdgcn_mfma_f32_16x16x32_bf16(qfl[kk], kfh, sc[t], 0, 0, 0);
      }
    }

    // online softmax: max-reduce only (sum comes from ones-column MFMA)
#pragma unroll
    for (int j = 0; j < 4; ++j) {
      const int q = q0 + w * 16 + g * 4 + j;
      float x0 = sc[0][j] * scale; if (s0 + c > q) x0 = -INFINITY;
      float x1 = sc[1][j] * scale; if (s0 + 16 + c > q) x1 = -INFINITY;
      float x2 = sc[2][j] * scale; if (s0 + 32 + c > q) x2 = -INFINITY;
      float x3 = sc[3][j] * scale; if (s0 + 48 + c > q) x3 = -INFINITY;
      float mx = fmaxf(fmaxf(x0, x1), fmaxf(x2, x3));
#pragma unroll
      for (int msk = 1; msk < 16; msk <<= 1) mx = fmaxf(mx, __shfl_xor(mx, msk));
      float mn = fmaxf(mi[j], mx);
      float a = __expf(mi[j] - mn);
      mi[j] = mn;
#pragma unroll
      for (int dt = 0; dt < 8; ++dt) o[dt][j] *= a;
      o2[j] *= a;
      Pl[w][(g * 4 + j) * VS + c]      = f2bf(__expf(x0 - mn));
      Pl[w][(g * 4 + j) * VS + 16 + c] = f2bf(__expf(x1 - mn));
      Pl[w][(g * 4 + j) * VS + 32 + c] = f2bf(__expf(x2 - mn));
      Pl[w][(g * 4 + j) * VS + 48 + c] = f2bf(__expf(x3 - mn));
    }

    // PV (+ ones-column accumulates the denominator)
#pragma unroll
    for (int ks = 0; ks < 2; ++ks) {
      bf16x8 pa = *(const bf16x8*)&Pl[w][c * VS + ks * 32 + g * 8];
#pragma unroll
      for (int dt = 0; dt < 8; ++dt) {
        bf16x8 vf = *(const bf16x8*)&Vt[(dt * 16 + c) * VS + ks * 32 + g * 8];
        o[dt] = __builtin_amdgcn_mfma_f32_16x16x32_bf16(pa, vf, o[dt], 0, 0, 0);
      }
      bf16x8 vo = *(const bf16x8*)&Vt[(128 + c) * VS + ks * 32 + g * 8];
      o2 = __builtin_amdgcn_mfma_f32_16x16x32_bf16(pa, vo, o2, 0, 0, 0);
    }
  }

  // epilogue: denominator lives in lane c==0 of each 16-lane group
#pragma unroll
  for (int j = 0; j < 4; ++j) {
    float li = __shfl(o2[j], l & 48);
    float inv = 1.f / li;
    u16* orow = Ob + (size_t)(q0 + w * 16 + g * 4 + j) * C + h * 128;
#pragma unroll
    for (int dt = 0; dt < 8; ++dt) orow[dt * 16 + c] = f2bf(o[dt][j] * inv);
  }
}

extern "C" void kernel_launch(void* const* d_in, const int* in_sizes, int n_in,
                              void* d_out, int out_size, void* d_ws, size_t ws_size,
                              hipStream_t stream) {
  const float* x = (const float*)d_in[0];
  const float* Wq = (const float*)d_in[1];
  const float* Wk = (const float*)d_in[2];
  const float* Wv = (const float*)d_in[3];
  const float* Wo = (const float*)d_in[4];
  const float* gq = (const float*)d_in[5];
  const float* gk = (const float*)d_in[6];
  const float* temp = (const float*)d_in[7];
  float* out = (float*)d_out;

  constexpr size_t M1 = (size_t)1024 * 1024;
  u16* ws16 = (u16*)d_ws;
  u16* xh  = ws16;                 // 4M u16
  u16* xl  = xh + 4 * M1;          // 4M
  u16* BTh = xl + 4 * M1;          // 6M  [3072][2048]: WqT_hi | WkT_hi | WvT
  u16* BTl = BTh + 6 * M1;         // 5M  [2560][2048]: WqT_lo | WkT_lo
  u16* WoT = BTl + 5 * M1;         // 4M
  u16* Vb  = WoT + 4 * M1;         // 1M  [2048][512]
  float* QKf = (float*)(Vb + 1 * M1);  // 5M f32 [2048][2560]
  u16* Qh = BTl;                   // aliases: BTh/BTl dead after k_gemmqkv
  u16* Ql = BTh;
  u16* Kh = BTh + 4 * M1;
  u16* Kl = BTh + 5 * M1;
  u16* Ob = xh;                    // xh dead after k_gemmqkv

  k_cvt2<<<(T * C / 4 + 255) / 256, 256, 0, stream>>>(x, xh, xl, T * C / 4);
  k_tcvt2<true><<<dim3(C / 32, C / 32), dim3(32, 8), 0, stream>>>(Wq, BTh, BTl, C, C);
  k_tcvt2<true><<<dim3(KVC / 32, C / 32), dim3(32, 8), 0, stream>>>(
      Wk, BTh + (size_t)C * C, BTl + (size_t)C * C, C, KVC);
  k_tcvt2<false><<<dim3(KVC / 32, C / 32), dim3(32, 8), 0, stream>>>(
      Wv, BTh + (size_t)2560 * C, nullptr, C, KVC);
  k_tcvt2<false><<<dim3(C / 32, C / 32), dim3(32, 8), 0, stream>>>(Wo, WoT, nullptr, C, C);
  k_gemmqkv<<<dim3(3072 / 128, T / 128), 256, 0, stream>>>(xh, xl, BTh, BTl, QKf, Vb);
  k_ln<<<T, 256, 0, stream>>>(QKf, gq, gk, Qh, Ql, Kh, Kl);
  k_attn<<<512, 256, 0, stream>>>(Qh, Ql, Kh, Kl, Vb, temp, Ob);
  k_gemm<<<dim3(C / 128, T / 128), 256, 0, stream>>>(Ob, WoT, out, T, C, C);

  (void)in_sizes; (void)n_in; (void)out_size; (void)ws_size;
}